// Round 3
// baseline (522.769 us; speedup 1.0000x reference)
//
#include <hip/hip_runtime.h>
#include <hip/hip_bf16.h>

#define LN_EPS 1e-5f

typedef __attribute__((ext_vector_type(8))) short short8_t;
typedef __attribute__((ext_vector_type(4))) float float4_t;

__device__ __forceinline__ float wsum64(float v) {
    v += __shfl_xor(v, 1);
    v += __shfl_xor(v, 2);
    v += __shfl_xor(v, 4);
    v += __shfl_xor(v, 8);
    v += __shfl_xor(v, 16);
    v += __shfl_xor(v, 32);
    return v;
}

__device__ __forceinline__ unsigned short f2bf(float x) {
    unsigned u = __builtin_bit_cast(unsigned, x);
    unsigned r = (u + 0x7FFFu + ((u >> 16) & 1u)) >> 16;
    return (unsigned short)r;
}

// ---------------- Sort pipeline: counting sort of edge ids by dst ----------------
__global__ __launch_bounds__(256) void hist_kernel(
    const int* __restrict__ dst, int* __restrict__ cnt, int E)
{
    const int i = blockIdx.x * blockDim.x + threadIdx.x;
    const int n = gridDim.x * blockDim.x;
    for (int e = i; e < E; e += n) atomicAdd(&cnt[dst[e]], 1);
}

// exclusive prefix sum of cnt[0..n) in place (single block)
__global__ __launch_bounds__(1024) void scan_kernel(int* __restrict__ cnt, int n)
{
    __shared__ int ls[1024];
    const int t = threadIdx.x;
    const int chunk = (n + 1023) >> 10;
    const int lo = min(t * chunk, n);
    const int hi = min(lo + chunk, n);
    int s = 0;
    for (int i = lo; i < hi; ++i) s += cnt[i];
    ls[t] = s;
    __syncthreads();
    for (int d = 1; d < 1024; d <<= 1) {
        int v = (t >= d) ? ls[t - d] : 0;
        __syncthreads();
        ls[t] += v;
        __syncthreads();
    }
    int run = ls[t] - s;   // exclusive prefix of this chunk
    for (int i = lo; i < hi; ++i) {
        int c = cnt[i];
        cnt[i] = run;
        run += c;
    }
}

__global__ __launch_bounds__(256) void scatter_kernel(
    const int* __restrict__ dst, int* __restrict__ cursor,
    int* __restrict__ perm, int E)
{
    const int i = blockIdx.x * blockDim.x + threadIdx.x;
    const int n = gridDim.x * blockDim.x;
    for (int e = i; e < E; e += n) {
        const int p = atomicAdd(&cursor[dst[e]], 1);
        perm[p] = e;
    }
}

// ---------------- Kernel A: hv = LN(GELU(X @ W_node)) ---------------- (unchanged)
__global__ __launch_bounds__(256) void node_proj_kernel(
    const float* __restrict__ X, const float* __restrict__ W,
    const float* __restrict__ g, const float* __restrict__ b,
    float* __restrict__ out, int nrows)
{
    __shared__ float xbuf[4][128];
    const int lane  = threadIdx.x & 63;
    const int wslot = threadIdx.x >> 6;
    const int gwave = (int)((blockIdx.x * blockDim.x + threadIdx.x) >> 6);
    const int nwave = (int)((gridDim.x * blockDim.x) >> 6);

    float w[128];
#pragma unroll
    for (int k = 0; k < 128; ++k) w[k] = W[k * 64 + lane];
    const float gg = g[lane], bb = b[lane];

    for (int r = gwave; r < nrows; r += nwave) {
        const float2 xv = *(const float2*)(X + (size_t)r * 128 + lane * 2);
        *(float2*)&xbuf[wslot][lane * 2] = xv;
        float a0 = 0.f, a1 = 0.f, a2 = 0.f, a3 = 0.f;
#pragma unroll
        for (int k4 = 0; k4 < 32; ++k4) {
            const float4 xq = *(const float4*)&xbuf[wslot][k4 * 4];
            a0 = fmaf(xq.x, w[4 * k4 + 0], a0);
            a1 = fmaf(xq.y, w[4 * k4 + 1], a1);
            a2 = fmaf(xq.z, w[4 * k4 + 2], a2);
            a3 = fmaf(xq.w, w[4 * k4 + 3], a3);
        }
        float p = (a0 + a1) + (a2 + a3);
        p = 0.5f * p * (1.0f + erff(p * 0.70710678118654752f));
        const float mean = wsum64(p) * (1.0f / 64.0f);
        const float dlt  = p - mean;
        const float var  = wsum64(dlt * dlt) * (1.0f / 64.0f);
        out[(size_t)r * 64 + lane] = dlt * rsqrtf(var + LN_EPS) * gg + bb;
    }
}

// ------- Kernel B (MFMA, sorted): per 64-edge tile (edges via perm, sorted by dst):
//   he = exp(LN(EF @ W_edge)); m = hv[src]*he; segmented-reduce by dst -> few atomics
__global__ __launch_bounds__(256) void edge_mfma_kernel(
    const float* __restrict__ EF, const float* __restrict__ W,
    const float* __restrict__ g, const float* __restrict__ b,
    const int* __restrict__ src, const int* __restrict__ dst,
    const int* __restrict__ perm,
    const float* __restrict__ hv, float* __restrict__ h, int nedges)
{
    __shared__ __align__(16) unsigned short Abuf[64 * 128];
    __shared__ __align__(16) unsigned short Wbuf[64 * 128];
    __shared__ __align__(16) float mls[64 * 68];   // stride 68: 2-way (free) banks
    __shared__ int srcb[64];
    __shared__ int dstb[64];

    const int t    = threadIdx.x;
    const int lane = t & 63;
    const int wv   = t >> 6;

    // ---- stage W^T into LDS (once per block): Wt[c][k], swizzle elem ^= (c&7)<<3
    {
        const int c  = t & 63;
        const int kb = (t >> 6) * 32;
#pragma unroll
        for (int kk = 0; kk < 32; kk += 8) {
            unsigned short tmp[8];
#pragma unroll
            for (int i = 0; i < 8; ++i)
                tmp[i] = f2bf(W[(size_t)(kb + kk + i) * 64 + c]);
            unsigned idx = (unsigned)(c * 128 + kb + kk) ^ (unsigned)((c & 7) << 3);
            *(uint4*)&Wbuf[idx] = *(const uint4*)tmp;
        }
    }

    float gv[4], bv[4];
#pragma unroll
    for (int ct = 0; ct < 4; ++ct) {
        gv[ct] = g[ct * 16 + (lane & 15)];
        bv[ct] = b[ct * 16 + (lane & 15)];
    }

    const int ntiles = (nedges + 63) >> 6;
    __syncthreads();

    for (int tile = blockIdx.x; tile < ntiles; tile += gridDim.x) {
        const int e0 = tile * 64;

        // ---- stage A tile via perm: EF[perm[e]][:] -> bf16 swizzled LDS
#pragma unroll
        for (int j = 0; j < 8; ++j) {
            const int f   = t + j * 256;
            const int row = f >> 5;
            const int k   = (f & 31) * 4;
            float4 v;
            const int e = e0 + row;
            if (e < nedges) {
                const int p = perm[e];
                v = *(const float4*)(EF + (size_t)p * 128 + k);
            } else v = make_float4(0.f, 0.f, 0.f, 0.f);
            unsigned short pk[4] = { f2bf(v.x), f2bf(v.y), f2bf(v.z), f2bf(v.w) };
            unsigned idx = (unsigned)(row * 128 + k) ^ (unsigned)((row & 7) << 3);
            *(uint2*)&Abuf[idx] = *(const uint2*)pk;
        }
        if (t < 64) {
            const int e = e0 + t;
            if (e < nedges) {
                const int p = perm[e];
                srcb[t] = src[p];
                dstb[t] = dst[p];
            } else { srcb[t] = 0; dstb[t] = -1; }
        }
        __syncthreads();

        // ---- MFMA: wave wv computes rows 16*wv..16*wv+15, all 64 cols
        const int r  = 16 * wv + (lane & 15);
        const int ka = (lane >> 4) * 8;
        short8_t a[4];
#pragma unroll
        for (int kt = 0; kt < 4; ++kt) {
            unsigned idx = (unsigned)(r * 128 + kt * 32 + ka) ^ (unsigned)((r & 7) << 3);
            a[kt] = *(const short8_t*)&Abuf[idx];
        }
        float4_t acc[4];
#pragma unroll
        for (int ct = 0; ct < 4; ++ct) {
            acc[ct].x = 0.f; acc[ct].y = 0.f; acc[ct].z = 0.f; acc[ct].w = 0.f;
        }
#pragma unroll
        for (int ct = 0; ct < 4; ++ct) {
            const int c = ct * 16 + (lane & 15);
#pragma unroll
            for (int kt = 0; kt < 4; ++kt) {
                unsigned idx = (unsigned)(c * 128 + kt * 32 + ka) ^ (unsigned)((c & 7) << 3);
                short8_t bfr = *(const short8_t*)&Wbuf[idx];
                acc[ct] = __builtin_amdgcn_mfma_f32_16x16x32_bf16(a[kt], bfr, acc[ct], 0, 0, 0);
            }
        }

        // ---- LN + exp + gather-mul -> m tile in LDS
        // C layout: col = ct*16 + (lane&15), row(local16) = (lane>>4)*4 + j
#pragma unroll
        for (int j = 0; j < 4; ++j) {
            float s = acc[0][j] + acc[1][j] + acc[2][j] + acc[3][j];
            s += __shfl_xor(s, 1); s += __shfl_xor(s, 2);
            s += __shfl_xor(s, 4); s += __shfl_xor(s, 8);
            const float mean = s * (1.0f / 64.0f);
            float d0 = acc[0][j] - mean, d1 = acc[1][j] - mean;
            float d2 = acc[2][j] - mean, d3 = acc[3][j] - mean;
            float vs = d0 * d0 + d1 * d1 + d2 * d2 + d3 * d3;
            vs += __shfl_xor(vs, 1); vs += __shfl_xor(vs, 2);
            vs += __shfl_xor(vs, 4); vs += __shfl_xor(vs, 8);
            const float inv = rsqrtf(vs * (1.0f / 64.0f) + LN_EPS);

            const int rloc = 16 * wv + (lane >> 4) * 4 + j;
            const int sn   = srcb[rloc];
            const int cb   = lane & 15;
            float dd[4] = { d0, d1, d2, d3 };
#pragma unroll
            for (int ct = 0; ct < 4; ++ct) {
                const float he = __expf(dd[ct] * inv * gv[ct] + bv[ct]);
                mls[rloc * 68 + ct * 16 + cb] = he * hv[(size_t)sn * 64 + ct * 16 + cb];
            }
        }
        __syncthreads();

        // ---- segmented reduce: thread t owns (col = t&63, rows q*16..q*16+15)
        {
            const int c = t & 63;
            const int q = t >> 6;
            int cur = -2;
            float acc2 = 0.f;
#pragma unroll
            for (int rr = 0; rr < 16; ++rr) {
                const int ridx = q * 16 + rr;
                const int d = dstb[ridx];
                const float v = mls[ridx * 68 + c];
                if (d != cur) {
                    if (cur >= 0) atomicAdd(h + (size_t)cur * 64 + c, acc2);
                    cur = d;
                    acc2 = v;
                } else acc2 += v;
            }
            if (cur >= 0) atomicAdd(h + (size_t)cur * 64 + c, acc2);
        }
        __syncthreads();   // Abuf/mls/dstb reused next tile
    }
}

// ---------------- Kernel C: out = LN(GELU(H @ W_out)) ---------------- (unchanged)
__global__ __launch_bounds__(256) void out_proj_kernel(
    const float* __restrict__ Hin, const float* __restrict__ W,
    const float* __restrict__ g, const float* __restrict__ b,
    float* __restrict__ out, int nrows)
{
    __shared__ float xbuf[4][64];
    const int lane  = threadIdx.x & 63;
    const int wslot = threadIdx.x >> 6;
    const int gwave = (int)((blockIdx.x * blockDim.x + threadIdx.x) >> 6);
    const int nwave = (int)((gridDim.x * blockDim.x) >> 6);

    float w0[64], w1[64];
#pragma unroll
    for (int k = 0; k < 64; ++k) {
        w0[k] = W[k * 128 + lane];
        w1[k] = W[k * 128 + 64 + lane];
    }
    const float g0 = g[lane], b0 = b[lane];
    const float g1 = g[64 + lane], b1 = b[64 + lane];

    for (int r = gwave; r < nrows; r += nwave) {
        xbuf[wslot][lane] = Hin[(size_t)r * 64 + lane];
        float a0 = 0.f, a1 = 0.f, a2 = 0.f, a3 = 0.f;
        float c0 = 0.f, c1 = 0.f, c2 = 0.f, c3 = 0.f;
#pragma unroll
        for (int k4 = 0; k4 < 16; ++k4) {
            const float4 xq = *(const float4*)&xbuf[wslot][k4 * 4];
            a0 = fmaf(xq.x, w0[4 * k4 + 0], a0);
            a1 = fmaf(xq.y, w0[4 * k4 + 1], a1);
            a2 = fmaf(xq.z, w0[4 * k4 + 2], a2);
            a3 = fmaf(xq.w, w0[4 * k4 + 3], a3);
            c0 = fmaf(xq.x, w1[4 * k4 + 0], c0);
            c1 = fmaf(xq.y, w1[4 * k4 + 1], c1);
            c2 = fmaf(xq.z, w1[4 * k4 + 2], c2);
            c3 = fmaf(xq.w, w1[4 * k4 + 3], c3);
        }
        float p0 = (a0 + a1) + (a2 + a3);
        float p1 = (c0 + c1) + (c2 + c3);
        p0 = 0.5f * p0 * (1.0f + erff(p0 * 0.70710678118654752f));
        p1 = 0.5f * p1 * (1.0f + erff(p1 * 0.70710678118654752f));
        const float mean = wsum64(p0 + p1) * (1.0f / 128.0f);
        const float d0 = p0 - mean, d1 = p1 - mean;
        const float var = wsum64(d0 * d0 + d1 * d1) * (1.0f / 128.0f);
        const float inv = rsqrtf(var + LN_EPS);
        out[(size_t)r * 128 + lane]      = d0 * inv * g0 + b0;
        out[(size_t)r * 128 + 64 + lane] = d1 * inv * g1 + b1;
    }
}

extern "C" void kernel_launch(void* const* d_in, const int* in_sizes, int n_in,
                              void* d_out, int out_size, void* d_ws, size_t ws_size,
                              hipStream_t stream) {
    const float* node_feats = (const float*)d_in[0];
    const float* edge_feats = (const float*)d_in[1];
    const int*   src        = (const int*)d_in[2];
    const int*   dst        = (const int*)d_in[3];
    const float* W_node     = (const float*)d_in[4];
    const float* ln_ng      = (const float*)d_in[5];
    const float* ln_nb      = (const float*)d_in[6];
    const float* W_edge     = (const float*)d_in[7];
    const float* ln_eg      = (const float*)d_in[8];
    const float* ln_eb      = (const float*)d_in[9];
    const float* W_out      = (const float*)d_in[10];
    const float* ln_og      = (const float*)d_in[11];
    const float* ln_ob      = (const float*)d_in[12];
    float* out = (float*)d_out;

    const int N = in_sizes[0] / 128;
    const int E = in_sizes[2];

    float* hv   = (float*)d_ws;                    // N*64 f32
    float* h    = hv + (size_t)N * 64;             // N*64 f32
    int*   cnt  = (int*)(h + (size_t)N * 64);      // N ints (hist -> offsets -> cursors)
    int*   perm = cnt + N;                         // E ints

    hipMemsetAsync(h, 0, (size_t)N * 64 * sizeof(float), stream);
    hipMemsetAsync(cnt, 0, (size_t)N * sizeof(int), stream);
    hist_kernel<<<1024, 256, 0, stream>>>(dst, cnt, E);
    scan_kernel<<<1, 1024, 0, stream>>>(cnt, N);
    scatter_kernel<<<1024, 256, 0, stream>>>(dst, cnt, perm, E);
    node_proj_kernel<<<640, 256, 0, stream>>>(node_feats, W_node, ln_ng, ln_nb, hv, N);
    edge_mfma_kernel<<<2048, 256, 0, stream>>>(edge_feats, W_edge, ln_eg, ln_eb,
                                               src, dst, perm, hv, h, E);
    out_proj_kernel<<<640, 256, 0, stream>>>(h, W_out, ln_og, ln_ob, out, N);
}

// Round 4
// 229.033 us; speedup vs baseline: 2.2825x; 2.2825x over previous
//
#include <hip/hip_runtime.h>
#include <hip/hip_bf16.h>

#define LN_EPS 1e-5f

typedef __attribute__((ext_vector_type(8))) short short8_t;
typedef __attribute__((ext_vector_type(4))) float float4_t;

__device__ __forceinline__ unsigned short f2bf(float x) {
    unsigned u = __builtin_bit_cast(unsigned, x);
    unsigned r = (u + 0x7FFFu + ((u >> 16) & 1u)) >> 16;
    return (unsigned short)r;
}

__device__ __forceinline__ float gelu_erf(float p) {
    return 0.5f * p * (1.0f + erff(p * 0.70710678118654752f));
}

// stage W^T (64 out-cols x 128 k) into swizzled LDS. 256 threads.
__device__ __forceinline__ void stage_w64(const float* __restrict__ W,
                                          unsigned short* Wbuf, int t) {
    const int c  = t & 63;
    const int kb = (t >> 6) * 32;
#pragma unroll
    for (int kk = 0; kk < 32; kk += 8) {
        unsigned short tmp[8];
#pragma unroll
        for (int i = 0; i < 8; ++i)
            tmp[i] = f2bf(W[(size_t)(kb + kk + i) * 64 + c]);
        unsigned idx = (unsigned)(c * 128 + kb + kk) ^ (unsigned)((c & 7) << 3);
        *(uint4*)&Wbuf[idx] = *(const uint4*)tmp;
    }
}

// ============ Kernel A: hv = LN(GELU(X @ W_node)) — barrier-free wave tiles ============
__global__ __launch_bounds__(256) void node_proj_kernel(
    const float* __restrict__ X, const float* __restrict__ W,
    const float* __restrict__ g, const float* __restrict__ b,
    float* __restrict__ out, int N)
{
    __shared__ __align__(16) unsigned short Wbuf[64 * 128];
    stage_w64(W, Wbuf, threadIdx.x);
    const int lane = threadIdx.x & 63;
    const int r16  = lane & 15;
    const int ks   = (lane >> 4) * 8;
    const int cq   = lane >> 4;
    float gv[4], bv[4];
#pragma unroll
    for (int ct = 0; ct < 4; ++ct) { gv[ct] = g[ct * 16 + r16]; bv[ct] = b[ct * 16 + r16]; }
    __syncthreads();

    const int gw = (int)((blockIdx.x * blockDim.x + threadIdx.x) >> 6);
    const int nw = (int)((gridDim.x * blockDim.x) >> 6);
    const int ntiles = (N + 15) >> 4;
    int tile = gw;
    if (tile >= ntiles) return;

    float4 pf[8];
    {
        const float* base = X + (size_t)min(tile * 16 + r16, N - 1) * 128;
#pragma unroll
        for (int kt = 0; kt < 4; ++kt) {
            pf[2 * kt]     = *(const float4*)(base + kt * 32 + ks);
            pf[2 * kt + 1] = *(const float4*)(base + kt * 32 + ks + 4);
        }
    }

    while (true) {
        const int r0 = tile * 16;
        short8_t a[4];
#pragma unroll
        for (int kt = 0; kt < 4; ++kt) {
            const float4 u = pf[2 * kt], v = pf[2 * kt + 1];
            short8_t t8;
            t8[0] = (short)f2bf(u.x); t8[1] = (short)f2bf(u.y);
            t8[2] = (short)f2bf(u.z); t8[3] = (short)f2bf(u.w);
            t8[4] = (short)f2bf(v.x); t8[5] = (short)f2bf(v.y);
            t8[6] = (short)f2bf(v.z); t8[7] = (short)f2bf(v.w);
            a[kt] = t8;
        }
        const int nt = tile + nw;
        if (nt < ntiles) {
            const float* base = X + (size_t)min(nt * 16 + r16, N - 1) * 128;
#pragma unroll
            for (int kt = 0; kt < 4; ++kt) {
                pf[2 * kt]     = *(const float4*)(base + kt * 32 + ks);
                pf[2 * kt + 1] = *(const float4*)(base + kt * 32 + ks + 4);
            }
        }

        float4_t acc[4];
#pragma unroll
        for (int ct = 0; ct < 4; ++ct) { acc[ct].x = 0.f; acc[ct].y = 0.f; acc[ct].z = 0.f; acc[ct].w = 0.f; }
#pragma unroll
        for (int ct = 0; ct < 4; ++ct) {
            const int c = ct * 16 + r16;
#pragma unroll
            for (int kt = 0; kt < 4; ++kt) {
                unsigned idx = (unsigned)(c * 128 + kt * 32 + ks) ^ (unsigned)((c & 7) << 3);
                short8_t bf = *(const short8_t*)&Wbuf[idx];
                acc[ct] = __builtin_amdgcn_mfma_f32_16x16x32_bf16(a[kt], bf, acc[ct], 0, 0, 0);
            }
        }

#pragma unroll
        for (int j = 0; j < 4; ++j) {
            float p0 = gelu_erf(acc[0][j]), p1 = gelu_erf(acc[1][j]);
            float p2 = gelu_erf(acc[2][j]), p3 = gelu_erf(acc[3][j]);
            float s = (p0 + p1) + (p2 + p3);
            s += __shfl_xor(s, 1); s += __shfl_xor(s, 2);
            s += __shfl_xor(s, 4); s += __shfl_xor(s, 8);
            const float mean = s * (1.0f / 64.0f);
            float d0 = p0 - mean, d1 = p1 - mean, d2 = p2 - mean, d3 = p3 - mean;
            float vs = d0 * d0 + d1 * d1 + d2 * d2 + d3 * d3;
            vs += __shfl_xor(vs, 1); vs += __shfl_xor(vs, 2);
            vs += __shfl_xor(vs, 4); vs += __shfl_xor(vs, 8);
            const float inv = rsqrtf(vs * (1.0f / 64.0f) + LN_EPS);
            const int r = r0 + cq * 4 + j;
            if (r < N) {
                float dd[4] = { d0, d1, d2, d3 };
#pragma unroll
                for (int ct = 0; ct < 4; ++ct)
                    out[(size_t)r * 64 + ct * 16 + r16] = dd[ct] * inv * gv[ct] + bv[ct];
            }
        }
        if (nt >= ntiles) break;
        tile = nt;
    }
}

// ============ Kernel B: edge — barrier-free wave tiles, direct atomics ============
__global__ __launch_bounds__(256) void edge_kernel(
    const float* __restrict__ EF, const float* __restrict__ W,
    const float* __restrict__ g, const float* __restrict__ b,
    const int* __restrict__ src, const int* __restrict__ dst,
    const float* __restrict__ hv, float* __restrict__ h, int E)
{
    __shared__ __align__(16) unsigned short Wbuf[64 * 128];
    stage_w64(W, Wbuf, threadIdx.x);
    const int lane = threadIdx.x & 63;
    const int r16  = lane & 15;
    const int ks   = (lane >> 4) * 8;
    const int cq   = lane >> 4;
    float gv[4], bv[4];
#pragma unroll
    for (int ct = 0; ct < 4; ++ct) { gv[ct] = g[ct * 16 + r16]; bv[ct] = b[ct * 16 + r16]; }
    __syncthreads();

    const int gw = (int)((blockIdx.x * blockDim.x + threadIdx.x) >> 6);
    const int nw = (int)((gridDim.x * blockDim.x) >> 6);
    const int ntiles = (E + 15) >> 4;
    int tile = gw;
    if (tile >= ntiles) return;

    float4 pf[8];
    int psv[4], pdv[4];
    {
        const float* base = EF + (size_t)min(tile * 16 + r16, E - 1) * 128;
#pragma unroll
        for (int kt = 0; kt < 4; ++kt) {
            pf[2 * kt]     = *(const float4*)(base + kt * 32 + ks);
            pf[2 * kt + 1] = *(const float4*)(base + kt * 32 + ks + 4);
        }
#pragma unroll
        for (int j = 0; j < 4; ++j) {
            const int e = min(tile * 16 + cq * 4 + j, E - 1);
            psv[j] = src[e]; pdv[j] = dst[e];
        }
    }

    while (true) {
        const int e0 = tile * 16;
        int sv[4], dv[4];
#pragma unroll
        for (int j = 0; j < 4; ++j) { sv[j] = psv[j]; dv[j] = pdv[j]; }

        // early hv gather — in flight across convert+MFMA+LN
        float hvv[4][4];
#pragma unroll
        for (int j = 0; j < 4; ++j)
#pragma unroll
            for (int ct = 0; ct < 4; ++ct)
                hvv[j][ct] = hv[(size_t)sv[j] * 64 + ct * 16 + r16];

        short8_t a[4];
#pragma unroll
        for (int kt = 0; kt < 4; ++kt) {
            const float4 u = pf[2 * kt], v = pf[2 * kt + 1];
            short8_t t8;
            t8[0] = (short)f2bf(u.x); t8[1] = (short)f2bf(u.y);
            t8[2] = (short)f2bf(u.z); t8[3] = (short)f2bf(u.w);
            t8[4] = (short)f2bf(v.x); t8[5] = (short)f2bf(v.y);
            t8[6] = (short)f2bf(v.z); t8[7] = (short)f2bf(v.w);
            a[kt] = t8;
        }

        // prefetch next tile (A rows + src/dst) — in flight across MFMA/LN/scatter
        const int nt = tile + nw;
        if (nt < ntiles) {
            const float* base = EF + (size_t)min(nt * 16 + r16, E - 1) * 128;
#pragma unroll
            for (int kt = 0; kt < 4; ++kt) {
                pf[2 * kt]     = *(const float4*)(base + kt * 32 + ks);
                pf[2 * kt + 1] = *(const float4*)(base + kt * 32 + ks + 4);
            }
#pragma unroll
            for (int j = 0; j < 4; ++j) {
                const int e = min(nt * 16 + cq * 4 + j, E - 1);
                psv[j] = src[e]; pdv[j] = dst[e];
            }
        }

        float4_t acc[4];
#pragma unroll
        for (int ct = 0; ct < 4; ++ct) { acc[ct].x = 0.f; acc[ct].y = 0.f; acc[ct].z = 0.f; acc[ct].w = 0.f; }
#pragma unroll
        for (int ct = 0; ct < 4; ++ct) {
            const int c = ct * 16 + r16;
#pragma unroll
            for (int kt = 0; kt < 4; ++kt) {
                unsigned idx = (unsigned)(c * 128 + kt * 32 + ks) ^ (unsigned)((c & 7) << 3);
                short8_t bf = *(const short8_t*)&Wbuf[idx];
                acc[ct] = __builtin_amdgcn_mfma_f32_16x16x32_bf16(a[kt], bf, acc[ct], 0, 0, 0);
            }
        }

#pragma unroll
        for (int j = 0; j < 4; ++j) {
            float s = acc[0][j] + acc[1][j] + acc[2][j] + acc[3][j];
            s += __shfl_xor(s, 1); s += __shfl_xor(s, 2);
            s += __shfl_xor(s, 4); s += __shfl_xor(s, 8);
            const float mean = s * (1.0f / 64.0f);
            float d0 = acc[0][j] - mean, d1 = acc[1][j] - mean;
            float d2 = acc[2][j] - mean, d3 = acc[3][j] - mean;
            float vs = d0 * d0 + d1 * d1 + d2 * d2 + d3 * d3;
            vs += __shfl_xor(vs, 1); vs += __shfl_xor(vs, 2);
            vs += __shfl_xor(vs, 4); vs += __shfl_xor(vs, 8);
            const float inv = rsqrtf(vs * (1.0f / 64.0f) + LN_EPS);
            const int e = e0 + cq * 4 + j;
            if (e < E) {
                float dd[4] = { d0, d1, d2, d3 };
#pragma unroll
                for (int ct = 0; ct < 4; ++ct) {
                    const float he = __expf(dd[ct] * inv * gv[ct] + bv[ct]);
                    atomicAdd(h + (size_t)dv[j] * 64 + ct * 16 + r16, he * hvv[j][ct]);
                }
            }
        }
        if (nt >= ntiles) break;
        tile = nt;
    }
}

// ============ Kernel C: out = LN(GELU(H @ W_out)) — K=64, 128 cols ============
__global__ __launch_bounds__(256) void out_proj_kernel(
    const float* __restrict__ Hin, const float* __restrict__ W,
    const float* __restrict__ g, const float* __restrict__ b,
    float* __restrict__ out, int N)
{
    __shared__ __align__(16) unsigned short Wbuf[128 * 64];
    {
        const int t  = threadIdx.x;
        const int c  = t & 127;
        const int k0 = (t >> 7) * 32;
#pragma unroll
        for (int kk = 0; kk < 32; kk += 8) {
            unsigned short tmp[8];
#pragma unroll
            for (int i = 0; i < 8; ++i)
                tmp[i] = f2bf(W[(size_t)(k0 + kk + i) * 128 + c]);
            unsigned idx = (unsigned)(c * 64 + k0 + kk) ^ (unsigned)((c & 7) << 3);
            *(uint4*)&Wbuf[idx] = *(const uint4*)tmp;
        }
    }
    const int lane = threadIdx.x & 63;
    const int r16  = lane & 15;
    const int ks   = (lane >> 4) * 8;
    const int cq   = lane >> 4;
    float gv[8], bv[8];
#pragma unroll
    for (int ct = 0; ct < 8; ++ct) { gv[ct] = g[ct * 16 + r16]; bv[ct] = b[ct * 16 + r16]; }
    __syncthreads();

    const int gw = (int)((blockIdx.x * blockDim.x + threadIdx.x) >> 6);
    const int nw = (int)((gridDim.x * blockDim.x) >> 6);
    const int ntiles = (N + 15) >> 4;
    int tile = gw;
    if (tile >= ntiles) return;

    float4 pf[4];
    {
        const float* base = Hin + (size_t)min(tile * 16 + r16, N - 1) * 64;
#pragma unroll
        for (int kt = 0; kt < 2; ++kt) {
            pf[2 * kt]     = *(const float4*)(base + kt * 32 + ks);
            pf[2 * kt + 1] = *(const float4*)(base + kt * 32 + ks + 4);
        }
    }

    while (true) {
        const int r0 = tile * 16;
        short8_t a[2];
#pragma unroll
        for (int kt = 0; kt < 2; ++kt) {
            const float4 u = pf[2 * kt], v = pf[2 * kt + 1];
            short8_t t8;
            t8[0] = (short)f2bf(u.x); t8[1] = (short)f2bf(u.y);
            t8[2] = (short)f2bf(u.z); t8[3] = (short)f2bf(u.w);
            t8[4] = (short)f2bf(v.x); t8[5] = (short)f2bf(v.y);
            t8[6] = (short)f2bf(v.z); t8[7] = (short)f2bf(v.w);
            a[kt] = t8;
        }
        const int nt = tile + nw;
        if (nt < ntiles) {
            const float* base = Hin + (size_t)min(nt * 16 + r16, N - 1) * 64;
#pragma unroll
            for (int kt = 0; kt < 2; ++kt) {
                pf[2 * kt]     = *(const float4*)(base + kt * 32 + ks);
                pf[2 * kt + 1] = *(const float4*)(base + kt * 32 + ks + 4);
            }
        }

        float4_t acc[8];
#pragma unroll
        for (int ct = 0; ct < 8; ++ct) { acc[ct].x = 0.f; acc[ct].y = 0.f; acc[ct].z = 0.f; acc[ct].w = 0.f; }
#pragma unroll
        for (int ct = 0; ct < 8; ++ct) {
            const int c = ct * 16 + r16;
#pragma unroll
            for (int kt = 0; kt < 2; ++kt) {
                unsigned idx = (unsigned)(c * 64 + kt * 32 + ks) ^ (unsigned)((c & 7) << 3);
                short8_t bf = *(const short8_t*)&Wbuf[idx];
                acc[ct] = __builtin_amdgcn_mfma_f32_16x16x32_bf16(a[kt], bf, acc[ct], 0, 0, 0);
            }
        }

#pragma unroll
        for (int j = 0; j < 4; ++j) {
            float p[8];
            float s = 0.f;
#pragma unroll
            for (int ct = 0; ct < 8; ++ct) { p[ct] = gelu_erf(acc[ct][j]); s += p[ct]; }
            s += __shfl_xor(s, 1); s += __shfl_xor(s, 2);
            s += __shfl_xor(s, 4); s += __shfl_xor(s, 8);
            const float mean = s * (1.0f / 128.0f);
            float vs = 0.f;
#pragma unroll
            for (int ct = 0; ct < 8; ++ct) { p[ct] -= mean; vs += p[ct] * p[ct]; }
            vs += __shfl_xor(vs, 1); vs += __shfl_xor(vs, 2);
            vs += __shfl_xor(vs, 4); vs += __shfl_xor(vs, 8);
            const float inv = rsqrtf(vs * (1.0f / 128.0f) + LN_EPS);
            const int r = r0 + cq * 4 + j;
            if (r < N) {
#pragma unroll
                for (int ct = 0; ct < 8; ++ct)
                    out[(size_t)r * 128 + ct * 16 + r16] = p[ct] * inv * gv[ct] + bv[ct];
            }
        }
        if (nt >= ntiles) break;
        tile = nt;
    }
}

extern "C" void kernel_launch(void* const* d_in, const int* in_sizes, int n_in,
                              void* d_out, int out_size, void* d_ws, size_t ws_size,
                              hipStream_t stream) {
    const float* node_feats = (const float*)d_in[0];
    const float* edge_feats = (const float*)d_in[1];
    const int*   src        = (const int*)d_in[2];
    const int*   dst        = (const int*)d_in[3];
    const float* W_node     = (const float*)d_in[4];
    const float* ln_ng      = (const float*)d_in[5];
    const float* ln_nb      = (const float*)d_in[6];
    const float* W_edge     = (const float*)d_in[7];
    const float* ln_eg      = (const float*)d_in[8];
    const float* ln_eb      = (const float*)d_in[9];
    const float* W_out      = (const float*)d_in[10];
    const float* ln_og      = (const float*)d_in[11];
    const float* ln_ob      = (const float*)d_in[12];
    float* out = (float*)d_out;

    const int N = in_sizes[0] / 128;
    const int E = in_sizes[2];

    float* hv = (float*)d_ws;                  // N*64 f32
    float* h  = hv + (size_t)N * 64;           // N*64 f32

    hipMemsetAsync(h, 0, (size_t)N * 64 * sizeof(float), stream);
    node_proj_kernel<<<784, 256, 0, stream>>>(node_feats, W_node, ln_ng, ln_nb, hv, N);
    edge_kernel<<<1024, 256, 0, stream>>>(edge_feats, W_edge, ln_eg, ln_eb,
                                          src, dst, hv, h, E);
    out_proj_kernel<<<784, 256, 0, stream>>>(h, W_out, ln_og, ln_ob, out, N);
}